// Round 1
// baseline (643.115 us; speedup 1.0000x reference)
//
#include <hip/hip_runtime.h>
#include <hip/hip_bf16.h>

typedef float f32x4 __attribute__((ext_vector_type(4)));
typedef __bf16 bf16x8 __attribute__((ext_vector_type(8)));
typedef unsigned short ushort_t;

#define GLDS16(gp, lp)                                                        \
  __builtin_amdgcn_global_load_lds(                                           \
      (__attribute__((address_space(1))) void*)(gp),                          \
      (__attribute__((address_space(3))) void*)(lp), 16, 0, 0)

__device__ __forceinline__ ushort_t f2bf(float f) {
  unsigned u = __float_as_uint(f);
  unsigned r = u + 0x7fffu + ((u >> 16) & 1u);  // round-to-nearest-even
  return (ushort_t)(r >> 16);
}

// ---------------------------------------------------------------------------
// Kernel 0: W1 [K=1024][N=1024] fp32 -> w1t [N][K] bf16 (transpose + convert)
// ---------------------------------------------------------------------------
__global__ __launch_bounds__(256) void prep_w1(const float* __restrict__ w1,
                                               ushort_t* __restrict__ w1t) {
  __shared__ ushort_t tile[64][80];  // pad to 160B rows: keeps 16B-aligned reads
  const int k0 = blockIdx.x * 64;
  const int n0 = blockIdx.y * 64;
  const int tid = threadIdx.x;
#pragma unroll
  for (int it = 0; it < 16; ++it) {
    int idx = it * 256 + tid;  // 0..4095 over 64x64
    int k = idx >> 6, n = idx & 63;
    tile[n][k] = f2bf(w1[(size_t)(k0 + k) * 1024 + n0 + n]);  // coalesced read
  }
  __syncthreads();
#pragma unroll
  for (int it = 0; it < 2; ++it) {
    int idx = it * 256 + tid;  // 512 stores of 8 halfs
    int n = idx >> 3, kk = (idx & 7) * 8;
    bf16x8 v = *(const bf16x8*)&tile[n][kk];
    *(bf16x8*)&w1t[(size_t)(n0 + n) * 1024 + k0 + kk] = v;
  }
}

// ---------------------------------------------------------------------------
// Kernel 1: logits GEMM. x[65536,1024] fp32 (converted on the fly) x
// w1t[1024,1024] bf16 -> h (in AGPRs only) -> relu -> dot w2 -> partial
// logit slices partial[16][65536] (slice = nblk*2 + colhalf). No atomics.
// ---------------------------------------------------------------------------
#define BM 128
#define BN 128
#define BK 32
#define NKT 32  // 1024 / BK

__global__ __launch_bounds__(256) void gemm_logits(
    const float* __restrict__ x, const ushort_t* __restrict__ w1t,
    const float* __restrict__ b1, const float* __restrict__ w2,
    float* __restrict__ partial) {
  __shared__ ushort_t As[BM][BK];  // 8 KB
  __shared__ ushort_t Bs[BN][BK];  // 8 KB
  const int tid = threadIdx.x;
  const int wave = tid >> 6, lane = tid & 63;
  const int quad = lane >> 4, lc = lane & 15;
  const int nblk = blockIdx.x;  // fastest-varying: 8 n-blocks share an x strip
  const int mblk = blockIdx.y;
  const int m0 = mblk * BM, n0 = nblk * BN;
  const int wm = (wave & 1) * 64, wn = (wave >> 1) * 64;

  f32x4 acc[4][4] = {};  // acc[mi][ni]: wave computes 64x64

  // A staging: 4 issues x (float4 load + cvt + ds_write_b64) per k-step
  const int ar = tid >> 3;        // 0..31
  const int ak = (tid & 7) * 4;   // 0..28
  const float* aptr[4];
  ushort_t* adst[4];
#pragma unroll
  for (int it = 0; it < 4; ++it) {
    aptr[it] = x + (size_t)(m0 + it * 32 + ar) * 1024 + ak;
    adst[it] = &As[it * 32 + ar][ak];
  }
  // B staging: 2 x global_load_lds dwordx4 per thread per k-step.
  // LDS dest per wave is contiguous (base + lane*16) as HW requires.
  const int g0 = tid, g1 = 256 + tid;
  const ushort_t* bptr0 = w1t + (size_t)(n0 + (g0 >> 2)) * 1024 + (g0 & 3) * 8;
  const ushort_t* bptr1 = w1t + (size_t)(n0 + (g1 >> 2)) * 1024 + (g1 & 3) * 8;
  ushort_t* bdst0 = &Bs[0][0] + (size_t)g0 * 8;
  ushort_t* bdst1 = &Bs[0][0] + (size_t)g1 * 8;

  for (int kt = 0; kt < NKT; ++kt) {
    const int k0 = kt * BK;
    __syncthreads();  // previous iteration's LDS reads complete
    GLDS16(bptr0 + k0, bdst0);
    GLDS16(bptr1 + k0, bdst1);
#pragma unroll
    for (int it = 0; it < 4; ++it) {
      float4 av = *(const float4*)(aptr[it] + k0);
      ushort4 p;
      p.x = f2bf(av.x); p.y = f2bf(av.y); p.z = f2bf(av.z); p.w = f2bf(av.w);
      *(ushort4*)adst[it] = p;
    }
    __syncthreads();  // staging (incl. vmcnt drain) complete

    bf16x8 af[4], bf[4];
#pragma unroll
    for (int mi = 0; mi < 4; ++mi)
      af[mi] = *(const bf16x8*)&As[wm + mi * 16 + lc][quad * 8];
#pragma unroll
    for (int ni = 0; ni < 4; ++ni)
      bf[ni] = *(const bf16x8*)&Bs[wn + ni * 16 + lc][quad * 8];
#pragma unroll
    for (int mi = 0; mi < 4; ++mi)
#pragma unroll
      for (int ni = 0; ni < 4; ++ni)
        acc[mi][ni] = __builtin_amdgcn_mfma_f32_16x16x32_bf16(
            af[mi], bf[ni], acc[mi][ni], 0, 0, 0);
  }

  // Epilogue: relu(h + b1) * w2, reduce this wave's 64 columns -> row partials
  float bv[4], wv[4];
#pragma unroll
  for (int ni = 0; ni < 4; ++ni) {
    int col = n0 + wn + ni * 16 + lc;
    bv[ni] = b1[col];
    wv[ni] = w2[col];
  }
#pragma unroll
  for (int mi = 0; mi < 4; ++mi) {
    float s0 = 0.f, s1 = 0.f, s2 = 0.f, s3 = 0.f;
#pragma unroll
    for (int ni = 0; ni < 4; ++ni) {
      f32x4 a = acc[mi][ni];
      float h;
      h = a[0] + bv[ni]; h = h > 0.f ? h : 0.f; s0 += h * wv[ni];
      h = a[1] + bv[ni]; h = h > 0.f ? h : 0.f; s1 += h * wv[ni];
      h = a[2] + bv[ni]; h = h > 0.f ? h : 0.f; s2 += h * wv[ni];
      h = a[3] + bv[ni]; h = h > 0.f ? h : 0.f; s3 += h * wv[ni];
    }
#pragma unroll
    for (int off = 1; off < 16; off <<= 1) {  // butterfly over the 16 columns
      s0 += __shfl_xor(s0, off, 64);
      s1 += __shfl_xor(s1, off, 64);
      s2 += __shfl_xor(s2, off, 64);
      s3 += __shfl_xor(s3, off, 64);
    }
    if (lc == 0) {
      int rowb = m0 + wm + mi * 16 + quad * 4;
      float* dst =
          partial + (size_t)(nblk * 2 + (wave >> 1)) * 65536 + rowb;
      dst[0] = s0; dst[1] = s1; dst[2] = s2; dst[3] = s3;
    }
  }
}

// ---------------------------------------------------------------------------
// Kernel 2: per 2x2 window: sum 16 logit slices, softmax over 4, weighted
// sum of the 4 fp32 x rows -> out[b, r, :]. One block per window.
// ---------------------------------------------------------------------------
__global__ __launch_bounds__(256) void pool_out(const float* __restrict__ x,
                                                const float* __restrict__ partial,
                                                const float* __restrict__ b2,
                                                float* __restrict__ out) {
  const int win = blockIdx.x;  // 0..16383 = b*1024 + r
  const int b = win >> 10;
  const int r = win & 1023;
  const int i = r >> 5, j = r & 31;
  const int t0 = i * 128 + j * 2;  // (2i)*64 + 2j
  const int tid = threadIdx.x;
  __shared__ float sl[4];
  if (tid < 64) {  // wave 0: 4 window positions x 16 slices
    const int k = tid >> 4, s = tid & 15;
    const int m = b * 4096 + t0 + (k >> 1) * 64 + (k & 1);
    float v = partial[(size_t)s * 65536 + m];
#pragma unroll
    for (int off = 1; off < 16; off <<= 1) v += __shfl_xor(v, off, 64);
    if (s == 0) sl[k] = v + b2[0];
  }
  __syncthreads();
  float l0 = sl[0], l1 = sl[1], l2 = sl[2], l3 = sl[3];
  float mx = fmaxf(fmaxf(l0, l1), fmaxf(l2, l3));
  float e0 = __expf(l0 - mx), e1 = __expf(l1 - mx);
  float e2 = __expf(l2 - mx), e3 = __expf(l3 - mx);
  float inv = 1.0f / (e0 + e1 + e2 + e3);
  e0 *= inv; e1 *= inv; e2 *= inv; e3 *= inv;

  const size_t base = ((size_t)b * 4096 + t0) * 1024;
  const float4* x0 = (const float4*)(x + base);
  const float4* x1 = (const float4*)(x + base + 1024);
  const float4* x2 = (const float4*)(x + base + 64 * 1024);
  const float4* x3 = (const float4*)(x + base + 65 * 1024);
  float4 v0 = x0[tid], v1 = x1[tid], v2 = x2[tid], v3 = x3[tid];
  float4 o;
  o.x = e0 * v0.x + e1 * v1.x + e2 * v2.x + e3 * v3.x;
  o.y = e0 * v0.y + e1 * v1.y + e2 * v2.y + e3 * v3.y;
  o.z = e0 * v0.z + e1 * v1.z + e2 * v2.z + e3 * v3.z;
  o.w = e0 * v0.w + e1 * v1.w + e2 * v2.w + e3 * v3.w;
  ((float4*)out)[(size_t)win * 256 + tid] = o;
}

// ---------------------------------------------------------------------------
extern "C" void kernel_launch(void* const* d_in, const int* in_sizes, int n_in,
                              void* d_out, int out_size, void* d_ws,
                              size_t ws_size, hipStream_t stream) {
  const float* x  = (const float*)d_in[0];  // [16, 4096, 1024]
  const float* W1 = (const float*)d_in[1];  // [1024, 1024]
  const float* b1 = (const float*)d_in[2];  // [1024]
  const float* W2 = (const float*)d_in[3];  // [1024, 1] -> flat [1024]
  const float* b2 = (const float*)d_in[4];  // [1]
  float* out = (float*)d_out;               // [16, 1024, 1024]

  ushort_t* w1t = (ushort_t*)d_ws;                          // 2 MB
  float* partial = (float*)((char*)d_ws + (2u << 20));      // 4 MB

  prep_w1<<<dim3(16, 16), 256, 0, stream>>>(W1, w1t);
  gemm_logits<<<dim3(8, 512), 256, 0, stream>>>(x, w1t, b1, W2, partial);
  pool_out<<<dim3(16384), 256, 0, stream>>>(x, partial, b2, out);
}